// Round 1
// baseline (85.861 us; speedup 1.0000x reference)
//
#include <hip/hip_runtime.h>
#include <hip/hip_bf16.h>

#define B_N 4096
#define E_N 64
#define D_N 1024

typedef __bf16 bf16x8 __attribute__((ext_vector_type(8)));
typedef __bf16 bf16x4 __attribute__((ext_vector_type(4)));
typedef float f32x4 __attribute__((ext_vector_type(4)));

// ws layout (bytes):
// [0, 4096)        sinv   (1024 f32)
// [4096, 4352)     Ak     (64 f32)
// [4352, 135424)   sk_bf16 [64][1024]   (sigma_inv * keys, K-major)
// [135424, 266496) kT_bf16 [1024][64]   (raw keys transposed, K(=e)-major)

__global__ __launch_bounds__(256) void prep_kernel(
    const float* __restrict__ keys, const float* __restrict__ lsig,
    float* __restrict__ sinv, float* __restrict__ ak,
    __bf16* __restrict__ sk, __bf16* __restrict__ kT)
{
  const int e = blockIdx.x;
  const int t = threadIdx.x;
  const float4 k4 = *(const float4*)(keys + e * D_N + 4 * t);
  const float4 l4 = *(const float4*)(lsig + 4 * t);
  float4 s4;
  s4.x = expf(-l4.x); s4.y = expf(-l4.y); s4.z = expf(-l4.z); s4.w = expf(-l4.w);
  if (e == 0) *(float4*)(sinv + 4 * t) = s4;
  const float4 sk4 = make_float4(s4.x * k4.x, s4.y * k4.y, s4.z * k4.z, s4.w * k4.w);
  bf16x4 skb;
  skb[0] = (__bf16)sk4.x; skb[1] = (__bf16)sk4.y; skb[2] = (__bf16)sk4.z; skb[3] = (__bf16)sk4.w;
  *(bf16x4*)(sk + e * D_N + 4 * t) = skb;
  kT[(4 * t + 0) * E_N + e] = (__bf16)k4.x;
  kT[(4 * t + 1) * E_N + e] = (__bf16)k4.y;
  kT[(4 * t + 2) * E_N + e] = (__bf16)k4.z;
  kT[(4 * t + 3) * E_N + e] = (__bf16)k4.w;
  float p = sk4.x * k4.x + sk4.y * k4.y + sk4.z * k4.z + sk4.w * k4.w;
  #pragma unroll
  for (int off = 32; off > 0; off >>= 1) p += __shfl_down(p, off);
  __shared__ float red[4];
  if ((t & 63) == 0) red[t >> 6] = p;
  __syncthreads();
  if (t == 0) ak[e] = red[0] + red[1] + red[2] + red[3];
}

__global__ __launch_bounds__(256) void main_kernel(
    const float* __restrict__ z, const float* __restrict__ sinv,
    const float* __restrict__ ak, const __bf16* __restrict__ sk,
    const __bf16* __restrict__ kT,
    float* __restrict__ out_sim, float* __restrict__ out_we)
{
  constexpr int ZS = D_N + 8;            // bf16 elems; +8 keeps 16B align, breaks bank pattern
  __shared__ __bf16 zlds[16 * ZS];       // 33 KB
  __shared__ float azp[16][16];
  __shared__ float azs[16];
  __shared__ float simb[16][68];         // +4 pad, 16B-aligned rows
  __shared__ __bf16 wlds[16][72];        // +8 pad, 16B-aligned rows

  const int t  = threadIdx.x;
  const int b0 = blockIdx.x * 16;

  // ---------- stage z -> bf16 LDS; accumulate Az = sum s*z^2 in fp32 ----------
  const int sr = t >> 4;                 // row 0..15 (16 threads per row)
  const int sc = t & 15;
  const float* zrow = z + (size_t)(b0 + sr) * D_N;
  float azacc = 0.f;
  #pragma unroll
  for (int l = 0; l < 16; ++l) {
    const int c = sc * 4 + l * 64;
    const float4 z4 = *(const float4*)(zrow + c);
    const float4 s4 = *(const float4*)(sinv + c);
    azacc += s4.x * z4.x * z4.x; azacc += s4.y * z4.y * z4.y;
    azacc += s4.z * z4.z * z4.z; azacc += s4.w * z4.w * z4.w;
    bf16x4 zb;
    zb[0] = (__bf16)z4.x; zb[1] = (__bf16)z4.y; zb[2] = (__bf16)z4.z; zb[3] = (__bf16)z4.w;
    *(bf16x4*)(&zlds[sr * ZS + c]) = zb;
  }
  azp[sr][sc] = azacc;
  __syncthreads();
  if (t < 16) {
    float s = 0.f;
    #pragma unroll
    for (int i = 0; i < 16; ++i) s += azp[t][i];
    azs[t] = s;
  }

  // ---------- GEMM1: G[16 rows][64 experts], one 16x16 e-tile per wave ----------
  const int wave = t >> 6;
  const int lane = t & 63;
  const int ln = lane & 15;              // n (e within tile) / m (A row)
  const int q  = lane >> 4;              // quad

  f32x4 acc = {0.f, 0.f, 0.f, 0.f};
  const __bf16* bp = sk + (size_t)(wave * 16 + ln) * D_N + q * 8;
  const __bf16* ap = &zlds[ln * ZS + q * 8];
  #pragma unroll 8
  for (int ks = 0; ks < 32; ++ks) {
    const bf16x8 bfr = *(const bf16x8*)(bp + ks * 32);
    const bf16x8 afr = *(const bf16x8*)(ap + ks * 32);
    acc = __builtin_amdgcn_mfma_f32_16x16x32_bf16(afr, bfr, acc, 0, 0, 0);
  }

  const float akv = ak[wave * 16 + ln];
  __syncthreads();                       // azs ready for everyone
  #pragma unroll
  for (int i = 0; i < 4; ++i) {
    const int row = q * 4 + i;           // C layout: row = quad*4+reg, col = lane&15
    const float dist = azs[row] + akv - 2.0f * acc[i];
    simb[row][wave * 16 + ln] = 1.0f / (1.0f + dist);
  }
  __syncthreads();

  // ---------- softmax over e (wave 0: 4 lanes per row, shfl reduce) ----------
  if (t < 64) {
    const int row = t >> 2, seg = t & 3;
    float v[16];
    #pragma unroll
    for (int i = 0; i < 16; ++i) v[i] = simb[row][seg * 16 + i];
    float mx = v[0];
    #pragma unroll
    for (int i = 1; i < 16; ++i) mx = fmaxf(mx, v[i]);
    mx = fmaxf(mx, __shfl_xor(mx, 1));
    mx = fmaxf(mx, __shfl_xor(mx, 2));
    float sum = 0.f;
    #pragma unroll
    for (int i = 0; i < 16; ++i) { v[i] = __expf(v[i] - mx); sum += v[i]; }
    sum += __shfl_xor(sum, 1);
    sum += __shfl_xor(sum, 2);
    const float inv = 1.0f / sum;
    #pragma unroll
    for (int i = 0; i < 16; ++i) wlds[row][seg * 16 + i] = (__bf16)(v[i] * inv);
  }
  __syncthreads();

  // ---------- similarity -> global (coalesced float4) ----------
  {
    const float4 sv = *(const float4*)&simb[t >> 4][(t & 15) * 4];
    *(float4*)(out_sim + (size_t)(b0 + (t >> 4)) * E_N + (t & 15) * 4) = sv;
  }

  // ---------- GEMM2: out[16 rows][1024] = w[16][64] @ keys[64][1024] ----------
  const bf16x8 a0 = *(const bf16x8*)&wlds[ln][q * 8];        // A: m=ln, k=e
  const bf16x8 a1 = *(const bf16x8*)&wlds[ln][32 + q * 8];
  #pragma unroll 4
  for (int i = 0; i < 16; ++i) {
    const int dt = wave + 4 * i;         // d-tile 0..63
    const int d0 = dt * 16;
    const __bf16* kp = kT + (size_t)(d0 + ln) * E_N + q * 8;  // B: n=d-col, k=e
    const bf16x8 b0f = *(const bf16x8*)(kp);
    const bf16x8 b1f = *(const bf16x8*)(kp + 32);
    f32x4 o = {0.f, 0.f, 0.f, 0.f};
    o = __builtin_amdgcn_mfma_f32_16x16x32_bf16(a0, b0f, o, 0, 0, 0);
    o = __builtin_amdgcn_mfma_f32_16x16x32_bf16(a1, b1f, o, 0, 0, 0);
    #pragma unroll
    for (int j = 0; j < 4; ++j)
      out_we[(size_t)(b0 + q * 4 + j) * D_N + d0 + ln] = o[j];
  }
}

extern "C" void kernel_launch(void* const* d_in, const int* in_sizes, int n_in,
                              void* d_out, int out_size, void* d_ws, size_t ws_size,
                              hipStream_t stream)
{
  const float* z    = (const float*)d_in[0];
  const float* keys = (const float*)d_in[1];
  const float* ls   = (const float*)d_in[2];
  float* out_sim = (float*)d_out;
  float* out_we  = out_sim + (size_t)B_N * E_N;
  char* ws = (char*)d_ws;
  float*  sinv = (float*)(ws);
  float*  ak   = (float*)(ws + 4096);
  __bf16* sk   = (__bf16*)(ws + 4352);
  __bf16* kT   = (__bf16*)(ws + 135424);
  prep_kernel<<<E_N, 256, 0, stream>>>(keys, ls, sinv, ak, sk, kT);
  main_kernel<<<B_N / 16, 256, 0, stream>>>(z, sinv, ak, sk, kT, out_sim, out_we);
}